// Round 11
// baseline (180.026 us; speedup 1.0000x reference)
//
#include <hip/hip_runtime.h>

typedef __bf16 bf16x8 __attribute__((ext_vector_type(8)));
typedef __bf16 bf16x4 __attribute__((ext_vector_type(4)));
typedef float f32x4 __attribute__((ext_vector_type(4)));
typedef unsigned short us8 __attribute__((ext_vector_type(8)));

__device__ __forceinline__ unsigned short f2bf(float f) {
  unsigned int u = __builtin_bit_cast(unsigned int, f);
  u += 0x7FFFu + ((u >> 16) & 1u);
  return (unsigned short)(u >> 16);
}
__device__ __forceinline__ float bf2f(unsigned short s) {
  return __builtin_bit_cast(float, (unsigned int)s << 16);
}

__device__ __forceinline__ void load_lds16(const void* g, void* l) {
  __builtin_amdgcn_global_load_lds(
      (const __attribute__((address_space(1))) unsigned int*)g,
      (__attribute__((address_space(3))) unsigned int*)l, 16, 0, 0);
}

#define MFMA16(a, b, c) __builtin_amdgcn_mfma_f32_16x16x32_bf16(a, b, c, 0, 0, 0)

constexpr int Dm = 1024, Ss = 2048;

// ---------------- LayerNorm: fp32 [4096][1024] -> bf16 ----------------
__global__ __launch_bounds__(256) void ln_kernel(
    const float* __restrict__ x, const float* __restrict__ gamma,
    const float* __restrict__ beta, unsigned short* __restrict__ out) {
  const int row = blockIdx.x;
  const int t = threadIdx.x;
  const float4 v = reinterpret_cast<const float4*>(x + (size_t)row * Dm)[t];
  float s = v.x + v.y + v.z + v.w;
  float ss = v.x * v.x + v.y * v.y + v.z * v.z + v.w * v.w;
#pragma unroll
  for (int off = 1; off < 64; off <<= 1) {
    s += __shfl_xor(s, off);
    ss += __shfl_xor(ss, off);
  }
  __shared__ float sb[8];
  const int lane = t & 63, wid = t >> 6;
  if (lane == 0) { sb[wid] = s; sb[4 + wid] = ss; }
  __syncthreads();
  s = sb[0] + sb[1] + sb[2] + sb[3];
  ss = sb[4] + sb[5] + sb[6] + sb[7];
  const float mu = s * (1.0f / Dm);
  const float var = ss * (1.0f / Dm) - mu * mu;
  const float rs = rsqrtf(var + 1e-5f);
  const float4 g = reinterpret_cast<const float4*>(gamma)[t];
  const float4 bt = reinterpret_cast<const float4*>(beta)[t];
  ushort4 pack;
  pack.x = f2bf((v.x - mu) * rs * g.x + bt.x);
  pack.y = f2bf((v.y - mu) * rs * g.y + bt.y);
  pack.z = f2bf((v.z - mu) * rs * g.z + bt.z);
  pack.w = f2bf((v.w - mu) * rs * g.w + bt.w);
  reinterpret_cast<ushort4*>(out + (size_t)row * Dm)[t] = pack;
}

// ------------- transpose fp32 [K][N] -> bf16 [N][K] -------------
__global__ __launch_bounds__(256) void transpose_kernel(
    const float* __restrict__ in, unsigned short* __restrict__ out, int K, int N) {
  __shared__ float tile[32][33];
  const int tx = threadIdx.x & 31, ty = threadIdx.x >> 5;
  const int n0 = blockIdx.x * 32, k0 = blockIdx.y * 32;
#pragma unroll
  for (int i = 0; i < 4; i++)
    tile[ty + i * 8][tx] = in[(size_t)(k0 + ty + i * 8) * N + n0 + tx];
  __syncthreads();
#pragma unroll
  for (int i = 0; i < 4; i++)
    out[(size_t)(n0 + ty + i * 8) * K + k0 + tx] = f2bf(tile[tx][ty + i * 8]);
}

// ------------- GEMM (m97 structure): A [M][K] bf16, Bt [N][K] bf16 -------------
// EPI==0: Q/K cols -> qkvraw bf16 (Q scaled); V cols -> vt [bh][hd][s] directly.
// EPI==1: C -> f32 + bias + resid.
template <int EPI>
__global__ __launch_bounds__(256) void gemm_kernel(
    const unsigned short* __restrict__ A, const unsigned short* __restrict__ Bt,
    int N, int K, int nbx, unsigned short* __restrict__ Cbf,
    unsigned short* __restrict__ vt, float* __restrict__ Cf,
    const float* __restrict__ bias, const float* __restrict__ resid) {
  __shared__ unsigned short Al[128 * 64];
  __shared__ unsigned short Bl[128 * 64];
  const int tid = threadIdx.x;
  const int lane = tid & 63, wid = tid >> 6;
  const int l15 = lane & 15, lg = lane >> 4;
  const int wm = wid >> 1, wn = wid & 1;
  const int cpx = gridDim.x >> 3;
  const int lb = (blockIdx.x & 7) * cpx + (blockIdx.x >> 3);
  const int bx = lb % nbx, by = lb / nbx;
  const int bm = by * 128, bn = bx * 128;
  const int r8 = lane >> 3;
  const int swz = ((lane & 7) * 16) ^ (r8 << 4);
  const char* Ab = (const char*)A;
  const char* Bb = (const char*)Bt;
  f32x4 acc[4][4] = {};
  for (int k0 = 0; k0 < K; k0 += 64) {
    __syncthreads();
#pragma unroll
    for (int p = 0; p < 4; p++) {
      const int row = p * 32 + wid * 8 + r8;
      load_lds16(Ab + ((size_t)(bm + row) * K + k0) * 2 + swz,
                 (char*)Al + p * 4096 + wid * 1024);
      load_lds16(Bb + ((size_t)(bn + row) * K + k0) * 2 + swz,
                 (char*)Bl + p * 4096 + wid * 1024);
    }
    __syncthreads();
#pragma unroll
    for (int kk = 0; kk < 2; kk++) {
      bf16x8 af[4], bfr[4];
#pragma unroll
      for (int mi = 0; mi < 4; mi++) {
        const int row = wm * 64 + mi * 16 + l15;
        af[mi] = *(const bf16x8*)((const char*)Al + row * 128 +
                                  ((kk * 64 + lg * 16) ^ ((row & 7) << 4)));
      }
#pragma unroll
      for (int nj = 0; nj < 4; nj++) {
        const int row = wn * 64 + nj * 16 + l15;
        bfr[nj] = *(const bf16x8*)((const char*)Bl + row * 128 +
                                   ((kk * 64 + lg * 16) ^ ((row & 7) << 4)));
      }
#pragma unroll
      for (int mi = 0; mi < 4; mi++)
#pragma unroll
        for (int nj = 0; nj < 4; nj++)
          acc[mi][nj] = MFMA16(af[mi], bfr[nj], acc[mi][nj]);
    }
  }
#pragma unroll
  for (int mi = 0; mi < 4; mi++)
#pragma unroll
    for (int nj = 0; nj < 4; nj++) {
      const int m = bm + wm * 64 + mi * 16 + lg * 4;
      const int n = bn + wn * 64 + nj * 16 + l15;
      if (EPI == 0) {
        if (n < 2048) {
          const float sc = (n < 1024) ? 0.180336880f : 1.0f;  // 0.125*log2(e)
#pragma unroll
          for (int r = 0; r < 4; r++)
            Cbf[(size_t)(m + r) * N + n] = f2bf(acc[mi][nj][r] * sc);
        } else {
          // V column: write straight to vt [bh][hd][s] (s = 4 consecutive rows)
          const int h = (n - 2048) >> 6, hd = (n - 2048) & 63;
          const int bq = m >> 11, s = m & 2047;
          bf16x4 o;
#pragma unroll
          for (int r = 0; r < 4; r++) o[r] = (__bf16)acc[mi][nj][r];
          *(bf16x4*)(vt + ((size_t)((bq << 4) + h) * 64 + hd) * 2048 + s) = o;
        }
      } else {
#pragma unroll
        for (int r = 0; r < 4; r++) {
          const size_t idx = (size_t)(m + r) * N + n;
          Cf[idx] = acc[mi][nj][r] + bias[n] + resid[idx];
        }
      }
    }
}

// ------------- flash attention: 8-wave blocks, 16x16 MFMA, 2-way KV-split -------------
// R9 structure + hoisted V-frag reads + unnormalized partial output.
// LDS = 16K Kb + 16K Vb + 32K Pl = 64K -> 2 blocks/CU -> 16 waves/CU.
__global__ __launch_bounds__(512, 4) void attn_kernel(
    const unsigned short* __restrict__ qkv, const unsigned short* __restrict__ vt,
    unsigned short* part0, unsigned short* part1, float* __restrict__ ml) {
  __shared__ unsigned short Kb[2][64 * 64];   // [kv][128B row] swizzled
  __shared__ unsigned short Vb[2][64 * 64];   // [hd][128B row of kv] swizzled
  __shared__ unsigned short Pl[8][32][64];    // per-wave [q][kv], XOR-swizzled
  const int tid = threadIdx.x, lane = tid & 63, wid = tid >> 6;  // wid 0..7
  const int l15 = lane & 15, lg = lane >> 4;
  const int lb = (blockIdx.x & 7) * 64 + (blockIdx.x >> 3);
  const int bh = lb >> 4, qt = (lb >> 1) & 7, half = lb & 1;
  const int b = bh >> 4, h = bh & 15;
  const int q0 = qt * 256 + wid * 32;
  const unsigned short* qbase = qkv + (size_t)(b * Ss) * 3072 + h * 64;
  const char* kbase = (const char*)(qkv + (size_t)(b * Ss) * 3072 + 1024 + h * 64);
  const char* vbase = (const char*)(vt + (size_t)bh * 64 * Ss);

  // Q fragments (B-operand: n=q=l15, k=d)
  bf16x8 qf[2][2];
#pragma unroll
  for (int qj = 0; qj < 2; qj++)
#pragma unroll
    for (int kk = 0; kk < 2; kk++)
      qf[qj][kk] = *reinterpret_cast<const bf16x8*>(
          &qbase[(size_t)(q0 + qj * 16 + l15) * 3072 + kk * 32 + lg * 8]);

  f32x4 accT[4][2] = {};        // O^T: [nj(hd)][qj]; lane: q=l15, hd=nj*16+lg*4+r
  float psum[2] = {0.f, 0.f};

  const int srow = lane >> 3;                      // 0..7
  const int swz = ((lane & 7) * 16) ^ (srow << 4);

// per wave: 1 K-load + 1 V-load (8 waves cover 64 rows each)
#define STAGE(bufi, t0v)                                                          \
  {                                                                               \
    load_lds16(kbase + (size_t)((t0v) + wid * 8 + srow) * 6144 + swz,             \
               (char*)&Kb[bufi][0] + wid * 1024);                                 \
    load_lds16(vbase + (size_t)(wid * 8 + srow) * 4096 + (size_t)(t0v) * 2 + swz, \
               (char*)&Vb[bufi][0] + wid * 1024);                                 \
  }

  const int t0base = half * 1024;
  STAGE(0, t0base);

  for (int itr = 0; itr < 16; itr++) {
    const int cur = itr & 1;
    // own 2 loads (issued one full iter ago) are the only outstanding VMEM.
    asm volatile("s_waitcnt vmcnt(0)" ::: "memory");
    __builtin_amdgcn_s_barrier();
    if (itr + 1 < 16) STAGE(cur ^ 1, t0base + (itr + 1) * 64);

    const char* kcur = (const char*)&Kb[cur][0];
    const char* vcur = (const char*)&Vb[cur][0];

    // S^T = K Q^T : lane holds q=l15 (+16qj), kv = kvi*16 + lg*4 + r
    f32x4 accs[4][2] = {};
    __builtin_amdgcn_s_setprio(1);
#pragma unroll
    for (int kk = 0; kk < 2; kk++) {
      bf16x8 kf[4];
#pragma unroll
      for (int kvi = 0; kvi < 4; kvi++) {
        const int rk = kvi * 16 + l15;
        kf[kvi] = *(const bf16x8*)(kcur + rk * 128 +
                                   ((kk * 64 + lg * 16) ^ ((rk & 7) << 4)));
      }
#pragma unroll
      for (int kvi = 0; kvi < 4; kvi++)
#pragma unroll
        for (int qj = 0; qj < 2; qj++)
          accs[kvi][qj] = MFMA16(kf[kvi], qf[qj][kk], accs[kvi][qj]);
    }
    __builtin_amdgcn_s_setprio(0);

    // hoisted V-fragment reads: independent of P, overlap with softmax VALU below
    bf16x8 vfr[2][4];
#pragma unroll
    for (int kk2 = 0; kk2 < 2; kk2++)
#pragma unroll
      for (int nj = 0; nj < 4; nj++) {
        const int rv = nj * 16 + l15;
        vfr[kk2][nj] = *(const bf16x8*)(vcur + rv * 128 +
                                        ((kk2 * 64 + lg * 16) ^ ((rv & 7) << 4)));
      }

    // softmax-lite: P = exp2(S), per-lane partial sums
#pragma unroll
    for (int qj = 0; qj < 2; qj++) {
      const int prow = qj * 16 + l15;
      char* prl = (char*)&Pl[wid][prow][0];
      float ps = 0.f;
#pragma unroll
      for (int kvi = 0; kvi < 4; kvi++) {
        bf16x4 pk;
#pragma unroll
        for (int r = 0; r < 4; r++) {
          const float p = exp2f(accs[kvi][qj][r]);
          ps += p;
          pk[r] = (__bf16)p;
        }
        *(bf16x4*)(prl + ((kvi * 32 + lg * 8) ^ ((l15 & 7) << 4))) = pk;
      }
      psum[qj] += ps;
    }

    // own P writes drained; Pl is per-wave -> no cross-wave sync needed
    asm volatile("s_waitcnt lgkmcnt(0)" ::: "memory");
    __builtin_amdgcn_sched_barrier(0);

    // O^T += V^T P : A=V^T (m=hd), B=P (n=q, k=kv)
    __builtin_amdgcn_s_setprio(1);
#pragma unroll
    for (int kk2 = 0; kk2 < 2; kk2++) {
      bf16x8 pf[2];
#pragma unroll
      for (int qj = 0; qj < 2; qj++)
        pf[qj] = *(const bf16x8*)((const char*)&Pl[wid][qj * 16 + l15][0] +
                                  ((kk2 * 64 + lg * 16) ^ ((l15 & 7) << 4)));
#pragma unroll
      for (int nj = 0; nj < 4; nj++)
#pragma unroll
        for (int qj = 0; qj < 2; qj++)
          accT[nj][qj] = MFMA16(vfr[kk2][nj], pf[qj], accT[nj][qj]);
    }
    __builtin_amdgcn_s_setprio(0);
  }

  // epilogue: reduce per-lane partial sums once; write UNNORMALIZED partial O
#pragma unroll
  for (int qj = 0; qj < 2; qj++) {
    psum[qj] += __shfl_xor(psum[qj], 16);
    psum[qj] += __shfl_xor(psum[qj], 32);
  }
  unsigned short* pout = half ? part1 : part0;
#pragma unroll
  for (int qj = 0; qj < 2; qj++) {
    const int q = q0 + qj * 16 + l15;
#pragma unroll
    for (int nj = 0; nj < 4; nj++) {
      bf16x4 o;
#pragma unroll
      for (int r = 0; r < 4; r++) o[r] = (__bf16)accT[nj][qj][r];
      *(bf16x4*)(pout + (size_t)(b * Ss + q) * Dm + h * 64 + nj * 16 + lg * 4) = o;
    }
  }
  if (lg == 0) {
#pragma unroll
    for (int qj = 0; qj < 2; qj++)
      ml[half * 65536 + bh * 2048 + q0 + qj * 16 + l15] = psum[qj];
  }
}

// ------------- combine: dots = (O0 + O1) / (p0 + p1) -------------
__global__ __launch_bounds__(256) void combine_kernel(
    const unsigned short* p0, const unsigned short* __restrict__ p1,
    const float* __restrict__ ml, unsigned short* dots) {
  const int t = blockIdx.x * 256 + threadIdx.x;
  const int hd8 = t & 7;
  const int h = (t >> 3) & 15;
  const int row = t >> 7;
  const int b = row >> 11, s = row & 2047;
  const int bh = b * 16 + h;
  const float inv = 1.0f / (ml[bh * 2048 + s] + ml[65536 + bh * 2048 + s]);
  const size_t off = (size_t)row * 1024 + h * 64 + hd8 * 8;
  const us8 a = *(const us8*)(p0 + off);
  const us8 c = *(const us8*)(p1 + off);
  us8 o;
#pragma unroll
  for (int j = 0; j < 8; j++) o[j] = f2bf((bf2f(a[j]) + bf2f(c[j])) * inv);
  *(us8*)(dots + off) = o;
}

extern "C" void kernel_launch(void* const* d_in, const int* in_sizes, int n_in,
                              void* d_out, int out_size, void* d_ws, size_t ws_size,
                              hipStream_t stream) {
  const float* tokens = (const float*)d_in[0];
  const float* ln_g = (const float*)d_in[1];
  const float* ln_b = (const float*)d_in[2];
  const float* w_qkv = (const float*)d_in[3];
  const float* w_proj = (const float*)d_in[4];
  const float* b_proj = (const float*)d_in[5];
  float* out = (float*)d_out;

  char* ws = (char*)d_ws;
  unsigned short* x_bf = (unsigned short*)(ws);              // 8 MB; reused as part0/dots
  unsigned short* wqkvT = (unsigned short*)(ws + 8388608);   // 6 MB
  unsigned short* wprojT = (unsigned short*)(ws + 14680064); // 2 MB
  unsigned short* qkvraw = (unsigned short*)(ws + 16777216); // 24 MB (V cols unused)
  unsigned short* vt = (unsigned short*)(ws + 41943040);     // 8 MB
  unsigned short* part1 = (unsigned short*)(ws + 50331648);  // 8 MB
  float* ml = (float*)(ws + 58720256);                       // 0.5 MB
  unsigned short* dots = x_bf;

  ln_kernel<<<4096, 256, 0, stream>>>(tokens, ln_g, ln_b, x_bf);
  transpose_kernel<<<dim3(3072 / 32, 1024 / 32), 256, 0, stream>>>(w_qkv, wqkvT, 1024, 3072);
  transpose_kernel<<<dim3(1024 / 32, 1024 / 32), 256, 0, stream>>>(w_proj, wprojT, 1024, 1024);
  gemm_kernel<0><<<768, 256, 0, stream>>>(
      x_bf, wqkvT, 3072, 1024, 24, qkvraw, vt, nullptr, nullptr, nullptr);
  attn_kernel<<<512, 512, 0, stream>>>(qkvraw, vt, dots, part1, ml);
  combine_kernel<<<2048, 256, 0, stream>>>(dots, part1, ml, dots);
  gemm_kernel<1><<<256, 256, 0, stream>>>(
      dots, wprojT, 1024, 1024, 8, nullptr, nullptr, out, b_proj, tokens);
}

// Round 12
// 137.383 us; speedup vs baseline: 1.3104x; 1.3104x over previous
//
#include <hip/hip_runtime.h>

typedef __bf16 bf16x8 __attribute__((ext_vector_type(8)));
typedef __bf16 bf16x4 __attribute__((ext_vector_type(4)));
typedef float f32x4 __attribute__((ext_vector_type(4)));
typedef unsigned short us8 __attribute__((ext_vector_type(8)));

__device__ __forceinline__ unsigned short f2bf(float f) {
  unsigned int u = __builtin_bit_cast(unsigned int, f);
  u += 0x7FFFu + ((u >> 16) & 1u);
  return (unsigned short)(u >> 16);
}
__device__ __forceinline__ float bf2f(unsigned short s) {
  return __builtin_bit_cast(float, (unsigned int)s << 16);
}

__device__ __forceinline__ void load_lds16(const void* g, void* l) {
  __builtin_amdgcn_global_load_lds(
      (const __attribute__((address_space(1))) unsigned int*)g,
      (__attribute__((address_space(3))) unsigned int*)l, 16, 0, 0);
}

#define MFMA16(a, b, c) __builtin_amdgcn_mfma_f32_16x16x32_bf16(a, b, c, 0, 0, 0)

constexpr int Dm = 1024, Ss = 2048;

// ---------------- LayerNorm: fp32 [4096][1024] -> bf16 ----------------
__global__ __launch_bounds__(256) void ln_kernel(
    const float* __restrict__ x, const float* __restrict__ gamma,
    const float* __restrict__ beta, unsigned short* __restrict__ out) {
  const int row = blockIdx.x;
  const int t = threadIdx.x;
  const float4 v = reinterpret_cast<const float4*>(x + (size_t)row * Dm)[t];
  float s = v.x + v.y + v.z + v.w;
  float ss = v.x * v.x + v.y * v.y + v.z * v.z + v.w * v.w;
#pragma unroll
  for (int off = 1; off < 64; off <<= 1) {
    s += __shfl_xor(s, off);
    ss += __shfl_xor(ss, off);
  }
  __shared__ float sb[8];
  const int lane = t & 63, wid = t >> 6;
  if (lane == 0) { sb[wid] = s; sb[4 + wid] = ss; }
  __syncthreads();
  s = sb[0] + sb[1] + sb[2] + sb[3];
  ss = sb[4] + sb[5] + sb[6] + sb[7];
  const float mu = s * (1.0f / Dm);
  const float var = ss * (1.0f / Dm) - mu * mu;
  const float rs = rsqrtf(var + 1e-5f);
  const float4 g = reinterpret_cast<const float4*>(gamma)[t];
  const float4 bt = reinterpret_cast<const float4*>(beta)[t];
  ushort4 pack;
  pack.x = f2bf((v.x - mu) * rs * g.x + bt.x);
  pack.y = f2bf((v.y - mu) * rs * g.y + bt.y);
  pack.z = f2bf((v.z - mu) * rs * g.z + bt.z);
  pack.w = f2bf((v.w - mu) * rs * g.w + bt.w);
  reinterpret_cast<ushort4*>(out + (size_t)row * Dm)[t] = pack;
}

// ------------- transpose fp32 [K][N] -> bf16 [N][K] -------------
__global__ __launch_bounds__(256) void transpose_kernel(
    const float* __restrict__ in, unsigned short* __restrict__ out, int K, int N) {
  __shared__ float tile[32][33];
  const int tx = threadIdx.x & 31, ty = threadIdx.x >> 5;
  const int n0 = blockIdx.x * 32, k0 = blockIdx.y * 32;
#pragma unroll
  for (int i = 0; i < 4; i++)
    tile[ty + i * 8][tx] = in[(size_t)(k0 + ty + i * 8) * N + n0 + tx];
  __syncthreads();
#pragma unroll
  for (int i = 0; i < 4; i++)
    out[(size_t)(n0 + ty + i * 8) * K + k0 + tx] = f2bf(tile[tx][ty + i * 8]);
}

// ------------- GEMM (m97 structure): A [M][K] bf16, Bt [N][K] bf16 -------------
// EPI==0 (BN=128): Q/K cols -> qkvraw (Q scaled); V cols -> vt [bh][hd][s] directly.
// EPI==1 (BN=64):  C -> f32 + bias + resid. 128xBN C-tile per block.
template <int EPI, int BN>
__global__ __launch_bounds__(256) void gemm_kernel(
    const unsigned short* __restrict__ A, const unsigned short* __restrict__ Bt,
    int N, int K, int nbx, unsigned short* __restrict__ Cbf,
    unsigned short* __restrict__ vt, float* __restrict__ Cf,
    const float* __restrict__ bias, const float* __restrict__ resid) {
  __shared__ unsigned short Al[128 * 64];
  __shared__ unsigned short Bl[BN * 64];
  constexpr int NJ = BN / 32;  // nj count per wave (4 for BN=128, 2 for BN=64)
  const int tid = threadIdx.x;
  const int lane = tid & 63, wid = tid >> 6;
  const int l15 = lane & 15, lg = lane >> 4;
  const int wm = wid >> 1, wn = wid & 1;
  const int cpx = gridDim.x >> 3;
  const int lb = (blockIdx.x & 7) * cpx + (blockIdx.x >> 3);
  const int bx = lb % nbx, by = lb / nbx;
  const int bm = by * 128, bn = bx * BN;
  const int r8 = lane >> 3;
  const int swz = ((lane & 7) * 16) ^ (r8 << 4);
  const char* Ab = (const char*)A;
  const char* Bb = (const char*)Bt;
  f32x4 acc[4][NJ] = {};
  for (int k0 = 0; k0 < K; k0 += 64) {
    __syncthreads();
#pragma unroll
    for (int p = 0; p < 4; p++) {
      const int row = p * 32 + wid * 8 + r8;
      load_lds16(Ab + ((size_t)(bm + row) * K + k0) * 2 + swz,
                 (char*)Al + p * 4096 + wid * 1024);
    }
#pragma unroll
    for (int p = 0; p < BN / 32; p++) {
      const int row = p * 32 + wid * 8 + r8;
      load_lds16(Bb + ((size_t)(bn + row) * K + k0) * 2 + swz,
                 (char*)Bl + p * 4096 + wid * 1024);
    }
    __syncthreads();
#pragma unroll
    for (int kk = 0; kk < 2; kk++) {
      bf16x8 af[4], bfr[NJ];
#pragma unroll
      for (int mi = 0; mi < 4; mi++) {
        const int row = wm * 64 + mi * 16 + l15;
        af[mi] = *(const bf16x8*)((const char*)Al + row * 128 +
                                  ((kk * 64 + lg * 16) ^ ((row & 7) << 4)));
      }
#pragma unroll
      for (int nj = 0; nj < NJ; nj++) {
        const int row = wn * (BN / 2) + nj * 16 + l15;
        bfr[nj] = *(const bf16x8*)((const char*)Bl + row * 128 +
                                   ((kk * 64 + lg * 16) ^ ((row & 7) << 4)));
      }
#pragma unroll
      for (int mi = 0; mi < 4; mi++)
#pragma unroll
        for (int nj = 0; nj < NJ; nj++)
          acc[mi][nj] = MFMA16(af[mi], bfr[nj], acc[mi][nj]);
    }
  }
#pragma unroll
  for (int mi = 0; mi < 4; mi++)
#pragma unroll
    for (int nj = 0; nj < NJ; nj++) {
      const int m = bm + wm * 64 + mi * 16 + lg * 4;
      const int n = bn + wn * (BN / 2) + nj * 16 + l15;
      if (EPI == 0) {
        if (n < 2048) {
          const float sc = (n < 1024) ? 0.180336880f : 1.0f;  // 0.125*log2(e)
#pragma unroll
          for (int r = 0; r < 4; r++)
            Cbf[(size_t)(m + r) * N + n] = f2bf(acc[mi][nj][r] * sc);
        } else {
          // V column: write straight to vt [bh][hd][s] (s = 4 consecutive rows)
          const int h = (n - 2048) >> 6, hd = (n - 2048) & 63;
          const int bq = m >> 11, s = m & 2047;
          bf16x4 o;
#pragma unroll
          for (int r = 0; r < 4; r++) o[r] = (__bf16)acc[mi][nj][r];
          *(bf16x4*)(vt + ((size_t)((bq << 4) + h) * 64 + hd) * 2048 + s) = o;
        }
      } else {
#pragma unroll
        for (int r = 0; r < 4; r++) {
          const size_t idx = (size_t)(m + r) * N + n;
          Cf[idx] = acc[mi][nj][r] + bias[n] + resid[idx];
        }
      }
    }
}

// ------------- flash attention: 8-wave blocks (Q=256), 2-way KV-split (R9) -------------
// LDS = 16K Kb + 16K Vb + 32K Pl = 64K -> 2 blocks/CU -> 16 waves/CU.
// softmax-lite (no max tracking): P = exp2(S), partial O normalized by psum,
// ml = log2(psum) for the combine.
__global__ __launch_bounds__(512) void attn_kernel(
    const unsigned short* __restrict__ qkv, const unsigned short* __restrict__ vt,
    unsigned short* part0, unsigned short* part1, float* __restrict__ ml) {
  __shared__ unsigned short Kb[2][64 * 64];   // [kv][128B row] swizzled
  __shared__ unsigned short Vb[2][64 * 64];   // [hd][128B row of kv] swizzled
  __shared__ unsigned short Pl[8][32][64];    // per-wave [q][kv], XOR-swizzled
  const int tid = threadIdx.x, lane = tid & 63, wid = tid >> 6;  // wid 0..7
  const int l15 = lane & 15, lg = lane >> 4;
  const int lb = (blockIdx.x & 7) * 64 + (blockIdx.x >> 3);
  const int bh = lb >> 4, qt = (lb >> 1) & 7, half = lb & 1;
  const int b = bh >> 4, h = bh & 15;
  const int q0 = qt * 256 + wid * 32;
  const unsigned short* qbase = qkv + (size_t)(b * Ss) * 3072 + h * 64;
  const char* kbase = (const char*)(qkv + (size_t)(b * Ss) * 3072 + 1024 + h * 64);
  const char* vbase = (const char*)(vt + (size_t)bh * 64 * Ss);

  // Q fragments (B-operand: n=q=l15, k=d)
  bf16x8 qf[2][2];
#pragma unroll
  for (int qj = 0; qj < 2; qj++)
#pragma unroll
    for (int kk = 0; kk < 2; kk++)
      qf[qj][kk] = *reinterpret_cast<const bf16x8*>(
          &qbase[(size_t)(q0 + qj * 16 + l15) * 3072 + kk * 32 + lg * 8]);

  f32x4 accT[4][2] = {};        // O^T: [nj(hd)][qj]; lane: q=l15, hd=nj*16+lg*4+r
  float psum[2] = {0.f, 0.f};

  const int srow = lane >> 3;                      // 0..7
  const int swz = ((lane & 7) * 16) ^ (srow << 4);

// per wave: 1 K-load + 1 V-load (8 waves cover 64 rows each)
#define STAGE(bufi, t0v)                                                          \
  {                                                                               \
    load_lds16(kbase + (size_t)((t0v) + wid * 8 + srow) * 6144 + swz,             \
               (char*)&Kb[bufi][0] + wid * 1024);                                 \
    load_lds16(vbase + (size_t)(wid * 8 + srow) * 4096 + (size_t)(t0v) * 2 + swz, \
               (char*)&Vb[bufi][0] + wid * 1024);                                 \
  }

  const int t0base = half * 1024;
  STAGE(0, t0base);

  for (int itr = 0; itr < 16; itr++) {
    const int cur = itr & 1;
    // own 2 loads (issued one full iter ago) are the only outstanding VMEM.
    asm volatile("s_waitcnt vmcnt(0)" ::: "memory");
    __builtin_amdgcn_s_barrier();
    if (itr + 1 < 16) STAGE(cur ^ 1, t0base + (itr + 1) * 64);

    const char* kcur = (const char*)&Kb[cur][0];
    const char* vcur = (const char*)&Vb[cur][0];

    // S^T = K Q^T : lane holds q=l15 (+16qj), kv = kvi*16 + lg*4 + r
    f32x4 accs[4][2] = {};
    __builtin_amdgcn_s_setprio(1);
#pragma unroll
    for (int kk = 0; kk < 2; kk++) {
      bf16x8 kf[4];
#pragma unroll
      for (int kvi = 0; kvi < 4; kvi++) {
        const int rk = kvi * 16 + l15;
        kf[kvi] = *(const bf16x8*)(kcur + rk * 128 +
                                   ((kk * 64 + lg * 16) ^ ((rk & 7) << 4)));
      }
#pragma unroll
      for (int kvi = 0; kvi < 4; kvi++)
#pragma unroll
        for (int qj = 0; qj < 2; qj++)
          accs[kvi][qj] = MFMA16(kf[kvi], qf[qj][kk], accs[kvi][qj]);
    }
    __builtin_amdgcn_s_setprio(0);

    // softmax-lite: P = exp2(S), per-lane partial sums
#pragma unroll
    for (int qj = 0; qj < 2; qj++) {
      const int prow = qj * 16 + l15;
      char* prl = (char*)&Pl[wid][prow][0];
      float ps = 0.f;
#pragma unroll
      for (int kvi = 0; kvi < 4; kvi++) {
        bf16x4 pk;
#pragma unroll
        for (int r = 0; r < 4; r++) {
          const float p = exp2f(accs[kvi][qj][r]);
          ps += p;
          pk[r] = (__bf16)p;
        }
        *(bf16x4*)(prl + ((kvi * 32 + lg * 8) ^ ((l15 & 7) << 4))) = pk;
      }
      psum[qj] += ps;
    }

    // own P writes drained; Pl is per-wave -> no cross-wave sync needed
    asm volatile("s_waitcnt lgkmcnt(0)" ::: "memory");
    __builtin_amdgcn_sched_barrier(0);

    // O^T += V^T P : A=V^T (m=hd), B=P (n=q, k=kv)
    __builtin_amdgcn_s_setprio(1);
#pragma unroll
    for (int kk2 = 0; kk2 < 2; kk2++) {
      bf16x8 pf[2], vf[4];
#pragma unroll
      for (int qj = 0; qj < 2; qj++)
        pf[qj] = *(const bf16x8*)((const char*)&Pl[wid][qj * 16 + l15][0] +
                                  ((kk2 * 64 + lg * 16) ^ ((l15 & 7) << 4)));
#pragma unroll
      for (int nj = 0; nj < 4; nj++) {
        const int rv = nj * 16 + l15;
        vf[nj] = *(const bf16x8*)(vcur + rv * 128 +
                                  ((kk2 * 64 + lg * 16) ^ ((rv & 7) << 4)));
      }
#pragma unroll
      for (int nj = 0; nj < 4; nj++)
#pragma unroll
        for (int qj = 0; qj < 2; qj++)
          accT[nj][qj] = MFMA16(vf[nj], pf[qj], accT[nj][qj]);
    }
    __builtin_amdgcn_s_setprio(0);
  }

  // epilogue: reduce per-lane partial sums once; q=l15 aligned
#pragma unroll
  for (int qj = 0; qj < 2; qj++) {
    psum[qj] += __shfl_xor(psum[qj], 16);
    psum[qj] += __shfl_xor(psum[qj], 32);
  }
  unsigned short* pout = half ? part1 : part0;
#pragma unroll
  for (int qj = 0; qj < 2; qj++) {
    const float rl = 1.0f / psum[qj];
    const int q = q0 + qj * 16 + l15;
#pragma unroll
    for (int nj = 0; nj < 4; nj++) {
      bf16x4 o;
#pragma unroll
      for (int r = 0; r < 4; r++) o[r] = (__bf16)(accT[nj][qj][r] * rl);
      *(bf16x4*)(pout + (size_t)(b * Ss + q) * Dm + h * 64 + nj * 16 + lg * 4) = o;
    }
  }
  if (lg == 0) {
#pragma unroll
    for (int qj = 0; qj < 2; qj++)
      ml[half * 65536 + bh * 2048 + q0 + qj * 16 + l15] = __log2f(psum[qj]);
  }
}

// ------------- combine: merge the two KV-halves -------------
__global__ __launch_bounds__(256) void combine_kernel(
    const unsigned short* p0, const unsigned short* __restrict__ p1,
    const float* __restrict__ ml, unsigned short* dots) {
  const int t = blockIdx.x * 256 + threadIdx.x;
  const int hd8 = t & 7;
  const int h = (t >> 3) & 15;
  const int row = t >> 7;
  const int b = row >> 11, s = row & 2047;
  const int bh = b * 16 + h;
  const float s0 = ml[bh * 2048 + s];
  const float s1 = ml[65536 + bh * 2048 + s];
  const float M = fmaxf(s0, s1);
  float w0 = exp2f(s0 - M), w1 = exp2f(s1 - M);
  const float inv = 1.0f / (w0 + w1);
  w0 *= inv; w1 *= inv;
  const size_t off = (size_t)row * 1024 + h * 64 + hd8 * 8;
  const us8 a = *(const us8*)(p0 + off);
  const us8 c = *(const us8*)(p1 + off);
  us8 o;
#pragma unroll
  for (int j = 0; j < 8; j++) o[j] = f2bf(w0 * bf2f(a[j]) + w1 * bf2f(c[j]));
  *(us8*)(dots + off) = o;
}

extern "C" void kernel_launch(void* const* d_in, const int* in_sizes, int n_in,
                              void* d_out, int out_size, void* d_ws, size_t ws_size,
                              hipStream_t stream) {
  const float* tokens = (const float*)d_in[0];
  const float* ln_g = (const float*)d_in[1];
  const float* ln_b = (const float*)d_in[2];
  const float* w_qkv = (const float*)d_in[3];
  const float* w_proj = (const float*)d_in[4];
  const float* b_proj = (const float*)d_in[5];
  float* out = (float*)d_out;

  char* ws = (char*)d_ws;
  unsigned short* x_bf = (unsigned short*)(ws);              // 8 MB; reused as part0/dots
  unsigned short* wqkvT = (unsigned short*)(ws + 8388608);   // 6 MB
  unsigned short* wprojT = (unsigned short*)(ws + 14680064); // 2 MB
  unsigned short* qkvraw = (unsigned short*)(ws + 16777216); // 24 MB (V cols unused)
  unsigned short* vt = (unsigned short*)(ws + 41943040);     // 8 MB
  unsigned short* part1 = (unsigned short*)(ws + 50331648);  // 8 MB
  float* ml = (float*)(ws + 58720256);                       // 0.5 MB
  unsigned short* dots = x_bf;

  ln_kernel<<<4096, 256, 0, stream>>>(tokens, ln_g, ln_b, x_bf);
  transpose_kernel<<<dim3(3072 / 32, 1024 / 32), 256, 0, stream>>>(w_qkv, wqkvT, 1024, 3072);
  transpose_kernel<<<dim3(1024 / 32, 1024 / 32), 256, 0, stream>>>(w_proj, wprojT, 1024, 1024);
  gemm_kernel<0, 128><<<768, 256, 0, stream>>>(
      x_bf, wqkvT, 3072, 1024, 24, qkvraw, vt, nullptr, nullptr, nullptr);
  attn_kernel<<<512, 512, 0, stream>>>(qkvraw, vt, dots, part1, ml);
  combine_kernel<<<2048, 256, 0, stream>>>(dots, part1, ml, dots);
  gemm_kernel<1, 64><<<512, 256, 0, stream>>>(
      dots, wprojT, 1024, 1024, 16, nullptr, nullptr, out, b_proj, tokens);
}